// Round 7
// baseline (50.437 us; speedup 1.0000x reference)
//
#include <hip/hip_runtime.h>
#include <hip/hip_bf16.h>
#include <stdint.h>

// Problem constants
#define BATCH 32
#define CIN   64
#define COUT  64
#define HIN   58
#define WIN   58
#define HOUT  56
#define WOUT  56
#define RSIZE 512
#define NB    10
#define EDIM  64
#define HID   128
#define CHW   (HIN*WIN)     // 3364
#define OHW   (HOUT*WOUT)   // 3136

typedef __attribute__((ext_vector_type(8)))  short short8;
typedef __attribute__((ext_vector_type(16))) float f32x16;

__device__ __forceinline__ unsigned short f2bf(float f) {
    unsigned int u = __builtin_bit_cast(unsigned int, f);
    u += 0x7fffu + ((u >> 16) & 1u);          // RNE
    return (unsigned short)(u >> 16);
}

// ---------------- Kernel 1: routing (R1 version, measured-fast) ----------------
__global__ __launch_bounds__(128) void routing_kernel(
    const float* __restrict__ rv, const float* __restrict__ W1,
    const float* __restrict__ b1, const float* __restrict__ W2,
    const float* __restrict__ b2, const float* __restrict__ emb,
    float* __restrict__ weights_out)
{
    const int b = blockIdx.x;
    const int t = threadIdx.x;
    __shared__ float s_rv[RSIZE];
    __shared__ float s_h[HID];
    __shared__ float s_r[EDIM];
    __shared__ float s_rnorm;
    __shared__ float s_sim[16];

    for (int i = t; i < RSIZE; i += 128) s_rv[i] = rv[b * RSIZE + i];
    __syncthreads();

    {
        float acc = b1[t];
        for (int k = 0; k < RSIZE; ++k) acc = fmaf(s_rv[k], W1[k * HID + t], acc);
        s_h[t] = fmaxf(acc, 0.0f);
    }
    __syncthreads();

    if (t < EDIM) {
        float acc = b2[t];
        for (int j = 0; j < HID; ++j) acc = fmaf(s_h[j], W2[j * EDIM + t], acc);
        s_r[t] = acc;
        float sq = acc * acc;
        #pragma unroll
        for (int off = 32; off > 0; off >>= 1) sq += __shfl_xor(sq, off);
        if (t == 0) s_rnorm = sqrtf(sq);
    }
    __syncthreads();

    if (t < NB) {
        float dot = 0.0f, nb2 = 0.0f;
        for (int e = 0; e < EDIM; ++e) {
            float ev = emb[t * EDIM + e];
            dot = fmaf(ev, s_r[e], dot);
            nb2 = fmaf(ev, ev, nb2);
        }
        s_sim[t] = dot / ((s_rnorm + 1e-8f) * (sqrtf(nb2) + 1e-8f));
    }
    __syncthreads();

    if (t == 0) {
        float m = -1e30f;
        #pragma unroll
        for (int n = 0; n < NB; ++n) m = fmaxf(m, s_sim[n]);
        float w[NB];
        float sum = 0.0f;
        #pragma unroll
        for (int n = 0; n < NB; ++n) { w[n] = __expf(s_sim[n] - m); sum += w[n]; }
        float inv = 1.0f / sum;
        float d = 0.0f;
        #pragma unroll
        for (int n = 0; n < NB; ++n) { w[n] *= inv; d += w[n]; }
        float invd = 1.0f / d;
        #pragma unroll
        for (int n = 0; n < NB; ++n) weights_out[b * NB + n] = w[n] * invd;
    }
}

// ---------------- Kernel 2: weight mix, wide grid ----------------
// 2048 blocks = (b, co), co-major (bid%8 == co%8 -> cw slice pinned to one XCD L2).
// 128 threads: stage 23KB cw slice, 72 threads each produce one 16B short8 run.
__global__ __launch_bounds__(128) void wmix3_kernel(
    const float* __restrict__ cw, const float* __restrict__ cbias,
    const float* __restrict__ wts,
    unsigned short* __restrict__ weffb, float* __restrict__ sbias_g)
{
    const int co = blockIdx.x & 63;
    const int b  = blockIdx.x >> 6;
    const int t  = threadIdx.x;

    __shared__ float scw[NB * 576];      // 23 KB
    __shared__ float s_w[NB];

    if (t < NB) s_w[t] = wts[b * NB + t];
    for (int i = t; i < 1440; i += 128) {
        const int n = i / 144, r4 = i - n * 144;
        ((float4*)scw)[n * 144 + r4] =
            *(const float4*)(cw + (size_t)(n * COUT + co) * 576 + r4 * 4);
    }
    __syncthreads();

    // run = s*8 + r8, r8 = ks*2+kg; output element base = ((b*72+run)*64+co)*8
    if (t < 72) {
        const int s  = t / 8;
        const int r8 = t - s * 8;
        short8 v8;
        #pragma unroll
        for (int c8 = 0; c8 < 8; ++c8) {
            const int cin = r8 * 8 + c8;
            float v = 0.0f;
            #pragma unroll
            for (int n = 0; n < NB; ++n)
                v = fmaf(s_w[n], scw[n * 576 + cin * 9 + s], v);
            v8[c8] = (short)f2bf(v);
        }
        *(short8*)&weffb[(((size_t)b * 72 + t) * 64 + co) * 8] = v8;
    }
    if (t == 127) {
        float v = 0.0f;
        #pragma unroll
        for (int n = 0; n < NB; ++n) v = fmaf(s_w[n], cbias[n * COUT + co], v);
        sbias_g[b * COUT + co] = v;
    }
}

// ---------------- Kernel 3: MFMA implicit-GEMM conv (unchanged, ~9.5us) ----------------
__global__ __launch_bounds__(256, 2) void conv3_kernel(
    const float* __restrict__ x, const unsigned short* __restrict__ weffb,
    const float* __restrict__ sbias_g, float* __restrict__ out)
{
    const int bid  = blockIdx.x;
    const int xcd  = bid & 7;
    const int slot = bid >> 3;
    const int b    = xcd + 8 * (slot / 28);
    const int tile = slot - (slot / 28) * 28;
    const int oh0  = tile * 2;

    const int t    = threadIdx.x;
    const int wid  = t >> 6;
    const int lane = t & 63;
    const int ln   = lane & 31;
    const int kg   = lane >> 5;

    __shared__ unsigned short xs[232 * 64];   // 29696 B
    __shared__ float sbias[COUT];

    if (t < COUT) sbias[t] = sbias_g[b * COUT + t];

    // stage full 232sp x 64cin tile, converting fp32->bf16 inline, XOR-swizzled
    const float* xg = x + (size_t)b * CIN * CHW + oh0 * WIN;
    #pragma unroll
    for (int k = 0; k < 8; ++k) {
        const int e = t + 256 * k;
        if (e < 1856) {
            const int cb = e / 232;
            const int sp = e - cb * 232;
            const float* gp = xg + (size_t)(cb * 8) * CHW + sp;
            short8 v;
            #pragma unroll
            for (int j = 0; j < 8; ++j)
                v[j] = (short)f2bf(gp[(size_t)j * CHW]);
            *(short8*)&xs[sp * 64 + (cb ^ (sp & 7)) * 8] = v;
        }
    }
    __syncthreads();

    const int p   = wid * 32 + ln;
    const bool valid = (p < 112);
    const int pc  = valid ? p : 111;
    const int r   = pc / 56, ow = pc - r * 56;
    const int sbase = r * WIN + ow;

    f32x16 acc[2];
    #pragma unroll
    for (int mt = 0; mt < 2; ++mt)
        #pragma unroll
        for (int j = 0; j < 16; ++j) acc[mt][j] = 0.0f;

    #pragma unroll
    for (int ks = 0; ks < 4; ++ks) {
        #pragma unroll
        for (int s = 0; s < 9; ++s) {
            const int kh = s / 3, kw = s - kh * 3;
            const unsigned short* ap =
                weffb + (((size_t)(b * 9 + s) * 4 + ks) * 2 + kg) * 512;
            const short8 a0 = *(const short8*)(ap + ln * 8);
            const short8 a1 = *(const short8*)(ap + (32 + ln) * 8);
            const int sp   = sbase + kh * WIN + kw;
            const int addr = (sp << 7) + ((((ks << 1) + kg) ^ (sp & 7)) << 4);
            const short8 bf = *(const short8*)((const char*)xs + addr);
            acc[0] = __builtin_amdgcn_mfma_f32_32x32x16_bf16(a0, bf, acc[0], 0, 0, 0);
            acc[1] = __builtin_amdgcn_mfma_f32_32x32x16_bf16(a1, bf, acc[1], 0, 0, 0);
        }
    }

    if (valid) {
        #pragma unroll
        for (int mt = 0; mt < 2; ++mt) {
            float* op = out + ((size_t)(b * COUT + mt * 32) * HOUT + oh0 + r) * WOUT + ow;
            #pragma unroll
            for (int reg = 0; reg < 16; ++reg) {
                const int co_l = (reg & 3) + 8 * (reg >> 2) + 4 * kg;
                op[(size_t)co_l * OHW] = acc[mt][reg] + sbias[mt * 32 + co_l];
            }
        }
    }
}

extern "C" void kernel_launch(void* const* d_in, const int* in_sizes, int n_in,
                              void* d_out, int out_size, void* d_ws, size_t ws_size,
                              hipStream_t stream) {
    const float* x    = (const float*)d_in[0];
    const float* rv   = (const float*)d_in[1];
    const float* W1   = (const float*)d_in[2];
    const float* b1   = (const float*)d_in[3];
    const float* W2   = (const float*)d_in[4];
    const float* b2   = (const float*)d_in[5];
    const float* emb  = (const float*)d_in[6];
    const float* cw   = (const float*)d_in[7];
    const float* cb   = (const float*)d_in[8];
    float* out = (float*)d_out;

    // ws layout (floats): wts@0 (320) | sbias_g@1024 (2048) | weffb@3072 (589824 floats as bf16)
    float* wts            = (float*)d_ws;
    float* sbias_g        = (float*)d_ws + 1024;
    unsigned short* weffb = (unsigned short*)((float*)d_ws + 3072);

    routing_kernel<<<dim3(BATCH), dim3(128), 0, stream>>>(rv, W1, b1, W2, b2, emb, wts);
    wmix3_kernel<<<dim3(BATCH * 64), dim3(128), 0, stream>>>(cw, cb, wts, weffb, sbias_g);
    conv3_kernel<<<dim3(BATCH * 28), dim3(256), 0, stream>>>(x, weffb, sbias_g, out);
}

// Round 8
// 39.545 us; speedup vs baseline: 1.2755x; 1.2755x over previous
//
#include <hip/hip_runtime.h>
#include <hip/hip_bf16.h>
#include <stdint.h>

// Problem constants
#define BATCH 32
#define CIN   64
#define COUT  64
#define HIN   58
#define WIN   58
#define HOUT  56
#define WOUT  56
#define RSIZE 512
#define NB    10
#define EDIM  64
#define HID   128
#define CHW   (HIN*WIN)     // 3364
#define OHW   (HOUT*WOUT)   // 3136

typedef __attribute__((ext_vector_type(8)))  short short8;
typedef __attribute__((ext_vector_type(16))) float f32x16;

__device__ __forceinline__ unsigned short f2bf(float f) {
    unsigned int u = __builtin_bit_cast(unsigned int, f);
    u += 0x7fffu + ((u >> 16) & 1u);          // RNE
    return (unsigned short)(u >> 16);
}

// ---------------- Kernel 1: routing (R6 version — part of measured-best config) ----------------
__global__ __launch_bounds__(512) void route_kernel(
    const float* __restrict__ rv, const float* __restrict__ W1,
    const float* __restrict__ b1, const float* __restrict__ W2,
    const float* __restrict__ b2, const float* __restrict__ emb,
    float* __restrict__ wts)
{
    const int b = blockIdx.x;
    const int t = threadIdx.x;

    __shared__ float s_rv[RSIZE];
    __shared__ float s_part[4 * HID];    // reused as [8][64] for W2
    __shared__ float s_h[HID];
    __shared__ float s_r[EDIM];
    __shared__ float s_rn;
    __shared__ float s_sim[NB];

    if (t < 128) ((float4*)s_rv)[t] = ((const float4*)(rv + (size_t)b * RSIZE))[t];
    __syncthreads();

    {
        const int h = t & 127, kq = t >> 7;
        float acc = 0.0f;
        const float* wp = W1 + (size_t)(kq * 128) * HID + h;
        const float* xp = s_rv + kq * 128;
        #pragma unroll 8
        for (int k = 0; k < 128; ++k) acc = fmaf(xp[k], wp[(size_t)k * HID], acc);
        s_part[kq * HID + h] = acc;
    }
    __syncthreads();
    if (t < HID)
        s_h[t] = fmaxf(s_part[t] + s_part[HID + t] + s_part[2 * HID + t] +
                       s_part[3 * HID + t] + b1[t], 0.0f);
    __syncthreads();

    {
        const int e = t & 63, kq = t >> 6;
        float acc = 0.0f;
        const float* wp = W2 + (size_t)(kq * 16) * EDIM + e;
        const float* hp = s_h + kq * 16;
        #pragma unroll
        for (int k = 0; k < 16; ++k) acc = fmaf(hp[k], wp[(size_t)k * EDIM], acc);
        s_part[kq * 64 + e] = acc;
    }
    __syncthreads();
    if (t < EDIM) {
        float r = b2[t];
        #pragma unroll
        for (int q = 0; q < 8; ++q) r += s_part[q * 64 + t];
        s_r[t] = r;
    }
    __syncthreads();

    if (t < 64) {
        float sq = s_r[t] * s_r[t];
        #pragma unroll
        for (int off = 32; off; off >>= 1) sq += __shfl_xor(sq, off);
        if (t == 0) s_rn = sqrtf(sq);
    }
    __syncthreads();

    {
        const int wid = t >> 6, lane = t & 63;
        for (int n = wid; n < NB; n += 8) {
            const float ev = emb[n * EDIM + lane];
            float dot = ev * s_r[lane];
            float nb2 = ev * ev;
            #pragma unroll
            for (int off = 32; off; off >>= 1) {
                dot += __shfl_xor(dot, off);
                nb2 += __shfl_xor(nb2, off);
            }
            if (lane == 0)
                s_sim[n] = dot / ((s_rn + 1e-8f) * (sqrtf(nb2) + 1e-8f));
        }
    }
    __syncthreads();

    if (t == 0) {
        float m = -1e30f;
        #pragma unroll
        for (int n = 0; n < NB; ++n) m = fmaxf(m, s_sim[n]);
        float w[NB], sum = 0.0f;
        #pragma unroll
        for (int n = 0; n < NB; ++n) { w[n] = __expf(s_sim[n] - m); sum += w[n]; }
        const float inv = 1.0f / sum;
        float d = 0.0f;
        #pragma unroll
        for (int n = 0; n < NB; ++n) { w[n] *= inv; d += w[n]; }
        const float invd = 1.0f / d;
        #pragma unroll
        for (int n = 0; n < NB; ++n) wts[b * NB + n] = w[n] * invd;
    }
}

// ---------------- Kernel 2: weight mix (R6 version — part of measured-best config) ----------------
__global__ __launch_bounds__(256) void wmix2_kernel(
    const float* __restrict__ cw, const float* __restrict__ cbias,
    const float* __restrict__ wts,
    unsigned short* __restrict__ weffb, float* __restrict__ sbias_g)
{
    const int co = blockIdx.x & 63;
    const int bq = blockIdx.x >> 6;
    const int t  = threadIdx.x;

    __shared__ float scw[NB * 576];      // 23 KB
    __shared__ float s_w[8 * NB];

    if (t < 8 * NB) s_w[t] = wts[bq * 8 * NB + t];
    for (int i = t; i < 1440; i += 256) {
        const int n = i / 144, r4 = i - n * 144;
        ((float4*)scw)[(size_t)n * 144 + r4] =
            *(const float4*)(cw + (size_t)(n * COUT + co) * 576 + r4 * 4);
    }
    __syncthreads();

    for (int i = t; i < 8 * 576; i += 256) {
        const int bl  = i / 576, rem = i - bl * 576;
        const int s   = rem >> 6, cin = rem & 63;
        float v = 0.0f;
        #pragma unroll
        for (int n = 0; n < NB; ++n)
            v = fmaf(s_w[bl * NB + n], scw[n * 576 + cin * 9 + s], v);
        const int b  = bq * 8 + bl;
        const int ks = cin >> 4, kg = (cin >> 3) & 1, c8 = cin & 7;
        weffb[((((size_t)(b * 9 + s) * 4 + ks) * 2 + kg) * 64 + co) * 8 + c8] = f2bf(v);
    }
    if (t < 8) {
        float v = 0.0f;
        #pragma unroll
        for (int n = 0; n < NB; ++n) v = fmaf(s_w[t * NB + n], cbias[n * COUT + co], v);
        sbias_g[(bq * 8 + t) * COUT + co] = v;
    }
}

// ---------------- Kernel 3: MFMA conv, (mt,nh) wave split (A loaded once, reused 2x) ----------------
// 896 blocks = (b, 2-row tile), XCD-swizzled; batch pinned to one XCD -> weffb[b]
// (73.7 KB) stays L2-resident. 4 waves: wave = (mt = co-half, nh); each wave
// owns 2 n-tiles and ONE co-half, so each af[9] block is loaded once per ks
// (36.9 KB A per wave, half of conv3's 73.7 KB).
__global__ __launch_bounds__(256, 2) void conv4_kernel(
    const float* __restrict__ x, const unsigned short* __restrict__ weffb,
    const float* __restrict__ sbias_g, float* __restrict__ out)
{
    const int bid  = blockIdx.x;
    const int xcd  = bid & 7;
    const int slot = bid >> 3;
    const int b    = xcd + 8 * (slot / 28);
    const int tile = slot - (slot / 28) * 28;
    const int oh0  = tile * 2;

    const int t    = threadIdx.x;
    const int wid  = t >> 6;
    const int lane = t & 63;
    const int ln   = lane & 31;
    const int kg   = lane >> 5;
    const int mt   = wid & 1;
    const int nh   = wid >> 1;

    __shared__ unsigned short xs[232 * 64];   // 29696 B
    __shared__ float sbias[COUT];

    if (t < COUT) sbias[t] = sbias_g[b * COUT + t];

    // stage full 232sp x 64cin tile, converting fp32->bf16 inline, XOR-swizzled
    const float* xg = x + (size_t)b * CIN * CHW + oh0 * WIN;
    #pragma unroll
    for (int k = 0; k < 8; ++k) {
        const int e = t + 256 * k;
        if (e < 1856) {
            const int cb = e / 232;
            const int sp = e - cb * 232;
            const float* gp = xg + (size_t)(cb * 8) * CHW + sp;
            short8 v;
            #pragma unroll
            for (int j = 0; j < 8; ++j)
                v[j] = (short)f2bf(gp[(size_t)j * CHW]);
            *(short8*)&xs[sp * 64 + (cb ^ (sp & 7)) * 8] = v;
        }
    }
    __syncthreads();

    // per-lane B spatial bases for this wave's 2 n-tiles
    int sbase[2]; int pq[2]; bool val[2];
    #pragma unroll
    for (int nt = 0; nt < 2; ++nt) {
        const int p = (nh * 2 + nt) * 32 + ln;
        val[nt] = (p < 112);
        const int pc = val[nt] ? p : 111;
        pq[nt] = pc;
        const int r = pc / 56, ow = pc - r * 56;
        sbase[nt] = r * WIN + ow;
    }

    f32x16 acc[2];
    #pragma unroll
    for (int nt = 0; nt < 2; ++nt)
        #pragma unroll
        for (int j = 0; j < 16; ++j) acc[nt][j] = 0.0f;

    // A base for this wave's co-half / k-group
    const unsigned short* abase =
        weffb + (size_t)b * 36864 + kg * 512 + (mt * 32 + ln) * 8;

    #pragma unroll
    for (int ks = 0; ks < 4; ++ks) {
        short8 af[9];
        #pragma unroll
        for (int s = 0; s < 9; ++s)
            af[s] = *(const short8*)(abase + (size_t)s * 4096 + ks * 1024);

        #pragma unroll
        for (int s = 0; s < 9; ++s) {
            const int kh = s / 3, kw = s - kh * 3;
            const int off = kh * WIN + kw;
            #pragma unroll
            for (int nt = 0; nt < 2; ++nt) {
                const int sp   = sbase[nt] + off;
                const int addr = (sp << 7) + ((((ks << 1) + kg) ^ (sp & 7)) << 4);
                const short8 bf = *(const short8*)((const char*)xs + addr);
                acc[nt] = __builtin_amdgcn_mfma_f32_32x32x16_bf16(af[s], bf, acc[nt], 0, 0, 0);
            }
        }
    }

    // epilogue: D col = ln (spatial), row = (reg&3)+8*(reg>>2)+4*kg (co within half)
    #pragma unroll
    for (int nt = 0; nt < 2; ++nt) {
        if (!val[nt]) continue;
        const int p = pq[nt];
        const int r = p / 56, ow = p - r * 56;
        float* op = out + ((size_t)(b * COUT + mt * 32) * HOUT + oh0 + r) * WOUT + ow;
        #pragma unroll
        for (int reg = 0; reg < 16; ++reg) {
            const int co_l = (reg & 3) + 8 * (reg >> 2) + 4 * kg;
            op[(size_t)co_l * OHW] = acc[nt][reg] + sbias[mt * 32 + co_l];
        }
    }
}

extern "C" void kernel_launch(void* const* d_in, const int* in_sizes, int n_in,
                              void* d_out, int out_size, void* d_ws, size_t ws_size,
                              hipStream_t stream) {
    const float* x    = (const float*)d_in[0];
    const float* rv   = (const float*)d_in[1];
    const float* W1   = (const float*)d_in[2];
    const float* b1   = (const float*)d_in[3];
    const float* W2   = (const float*)d_in[4];
    const float* b2   = (const float*)d_in[5];
    const float* emb  = (const float*)d_in[6];
    const float* cw   = (const float*)d_in[7];
    const float* cb   = (const float*)d_in[8];
    float* out = (float*)d_out;

    // ws layout (floats): wts@0 (320) | sbias_g@1024 (2048) | weffb@3072 (294912 floats as bf16)
    float* wts            = (float*)d_ws;
    float* sbias_g        = (float*)d_ws + 1024;
    unsigned short* weffb = (unsigned short*)((float*)d_ws + 3072);

    route_kernel<<<dim3(BATCH), dim3(512), 0, stream>>>(rv, W1, b1, W2, b2, emb, wts);
    wmix2_kernel<<<dim3(256), dim3(256), 0, stream>>>(cw, cb, wts, weffb, sbias_g);
    conv4_kernel<<<dim3(BATCH * 28), dim3(256), 0, stream>>>(x, weffb, sbias_g, out);
}